// Round 8
// baseline (128.137 us; speedup 1.0000x reference)
//
#include <hip/hip_runtime.h>
#include <math.h>

#ifndef M_PI
#define M_PI 3.14159265358979323846
#endif

#define NFILT   10
#define NSEC    5                   // five pair-cascade sections
#define THREADS 1024
#define CHUNK   32
#define SEGLEN  (THREADS * CHUNK)   // 32768
#define NSEG    2                   // L = 65536
#define LTOT    (SEGLEN * NSEG)
#define NWAVE   (THREADS / 64)      // 16

#define WS_STRIDE 1152              // floats per batch (16B-aligned)
#define MATS_OFF  160               // coefs: j*32 (j<5); matrices after

// ---------------- precompute (f64) ----------------

__device__ inline void mm4d(const double* X, const double* Y, double* Z) {
    #pragma unroll
    for (int r = 0; r < 4; ++r)
        #pragma unroll
        for (int c = 0; c < 4; ++c)
            Z[r*4+c] = X[r*4+0]*Y[c] + X[r*4+1]*Y[4+c] + X[r*4+2]*Y[8+c] + X[r*4+3]*Y[12+c];
}

__device__ inline void biquad_coefs(int k, double w0r, double qir, double gr,
                                    double* bo, double* ao) {
    const double w0 = M_PI / (1.0 + exp(-w0r));
    const double qi = exp(qir);
    const double A  = exp(gr);
    const double cw = cos(w0);
    const double al = sin(w0) * qi * 0.5;
    double B0, B1, B2, A0, A1, A2;
    if (k == 0) {                       // low shelf
        const double Ap1 = A + 1.0, Am1 = A - 1.0, tsa = 2.0 * sqrt(A) * al;
        B0 = A * (Ap1 - Am1 * cw + tsa);
        B1 = 2.0 * A * (Am1 - Ap1 * cw);
        B2 = A * (Ap1 - Am1 * cw - tsa);
        A0 = Ap1 + Am1 * cw + tsa;
        A1 = -2.0 * (Am1 + Ap1 * cw);
        A2 = Ap1 + Am1 * cw - tsa;
    } else if (k == NFILT - 1) {        // high shelf
        const double Ap1 = A + 1.0, Am1 = A - 1.0, tsa = 2.0 * sqrt(A) * al;
        B0 = A * (Ap1 + Am1 * cw + tsa);
        B1 = -2.0 * A * (Am1 + Ap1 * cw);
        B2 = A * (Ap1 + Am1 * cw - tsa);
        A0 = Ap1 - Am1 * cw + tsa;
        A1 = 2.0 * (Am1 - Ap1 * cw);
        A2 = Ap1 - Am1 * cw - tsa;
    } else {                            // peaking
        const double aA = al * A, aiA = al / A;
        B0 = 1.0 + aA;  B1 = -2.0 * cw; B2 = 1.0 - aA;
        A0 = 1.0 + aiA; A1 = B1;        A2 = 1.0 - aiA;
    }
    const double inv = 1.0 / A0;
    bo[0] = B0 * inv; bo[1] = B1 * inv; bo[2] = B2 * inv;
    ao[0] = 1.0;      ao[1] = A1 * inv; ao[2] = A2 * inv;
}

// Per batch b, per section j: biquads (2j,2j+1) kept in CASCADE form.
// Stacked state s = (vA_{-1}, vA_{-2}, vB_{-1}, vB_{-2}).
// Writes 10 f32 coefs + 4x4 pair-transfer powers M^(32*2^r), r=0..10.
__global__ void eq_precompute_kernel(const float* __restrict__ w0_in,
                                     const float* __restrict__ qinv_in,
                                     const float* __restrict__ gain_in,
                                     float* __restrict__ ws)
{
    const int b = blockIdx.x;
    const int j = threadIdx.x;
    if (j >= NSEC) return;

    double bA[3], aA[3], bB[3], aB[3];
    const int k0 = 2 * j, k1 = 2 * j + 1;
    biquad_coefs(k0, (double)w0_in[b*NFILT+k0], (double)qinv_in[b*NFILT+k0],
                 (double)gain_in[b*NFILT+k0], bA, aA);
    biquad_coefs(k1, (double)w0_in[b*NFILT+k1], (double)qinv_in[b*NFILT+k1],
                 (double)gain_in[b*NFILT+k1], bB, aB);

    float* wb = ws + (size_t)b * WS_STRIDE;
    float* cj = wb + j * 32;
    cj[0] = (float)bA[0]; cj[1] = (float)bA[1]; cj[2] = (float)bA[2];
    cj[3] = (float)aA[1]; cj[4] = (float)aA[2];
    cj[5] = (float)bB[0]; cj[6] = (float)bB[1]; cj[7] = (float)bB[2];
    cj[8] = (float)aB[1]; cj[9] = (float)aB[2];

    // 32-sample homogeneous pair transfer: columns = response to basis states
    double M[16], T[16];
    #pragma unroll
    for (int c = 0; c < 4; ++c) {
        double vA1 = (c==0) ? 1.0 : 0.0, vA2 = (c==1) ? 1.0 : 0.0;
        double vB1 = (c==2) ? 1.0 : 0.0, vB2 = (c==3) ? 1.0 : 0.0;
        for (int t = 0; t < CHUNK; ++t) {
            const double vA = -aA[1]*vA1 - aA[2]*vA2;              // cA = 0
            const double cB = bB[0]*vA + bB[1]*vA1 + bB[2]*vA2;
            const double vB = cB - aB[1]*vB1 - aB[2]*vB2;
            vA2 = vA1; vA1 = vA; vB2 = vB1; vB1 = vB;
        }
        M[0*4+c] = vA1; M[1*4+c] = vA2; M[2*4+c] = vB1; M[3*4+c] = vB2;
    }
    for (int r = 0; r <= 10; ++r) {     // M^(32*2^r)
        #pragma unroll
        for (int e = 0; e < 16; ++e)
            wb[MATS_OFF + (j*11 + r)*16 + e] = (float)M[e];
        mm4d(M, M, T);
        #pragma unroll
        for (int e = 0; e < 16; ++e) M[e] = T[e];
    }
}

// ---------------- main kernel ----------------

__device__ inline void mv4(const float4 r0, const float4 r1, const float4 r2, const float4 r3,
                           float x, float y, float z, float w,
                           float& ox, float& oy, float& oz, float& ow) {
    ox = r0.x*x + r0.y*y + r0.z*z + r0.w*w;
    oy = r1.x*x + r1.y*y + r1.z*z + r1.w*w;
    oz = r2.x*x + r2.y*y + r2.z*z + r2.w*w;
    ow = r3.x*x + r3.y*y + r3.z*z + r3.w*w;
}

__device__ inline void mva4(const float4 r0, const float4 r1, const float4 r2, const float4 r3,
                            float tx, float ty, float tz, float tw,
                            float& sx, float& sy_, float& sz, float& sw) {
    sx  += r0.x*tx + r0.y*ty + r0.z*tz + r0.w*tw;
    sy_ += r1.x*tx + r1.y*ty + r1.z*tz + r1.w*tw;
    sz  += r2.x*tx + r2.y*ty + r2.z*tz + r2.w*tw;
    sw  += r3.x*tx + r3.y*ty + r3.z*tz + r3.w*tw;
}

__global__ void
__attribute__((amdgpu_flat_work_group_size(THREADS, THREADS)))
__attribute__((amdgpu_waves_per_eu(4, 4)))
eq_cascade_kernel(const float* __restrict__ x,
                  float* __restrict__ out,
                  const float* __restrict__ ws)
{
    __shared__ float2 bnd[THREADS];      // raw-x chunk boundary (x_{-1}, x_{-2})
    __shared__ float4 waveP[2][NWAVE];   // per-wave inclusive particular totals
    __shared__ float4 sy[2][NSEC];       // section true end-state, dbuf by segment
    __shared__ float2 sxs[2];            // raw-x segment-end window

    const int tid  = threadIdx.x;
    const int lane = tid & 63;
    const int wid  = tid >> 6;
    const int b    = blockIdx.x;
    const float* __restrict__ wsb = ws + (size_t)b * WS_STRIDE;

    if (tid < NSEC) sy[0][tid] = make_float4(0.f, 0.f, 0.f, 0.f);
    if (tid == 0)   sxs[0]     = make_float2(0.f, 0.f);

    const float* xb = x   + (size_t)b * LTOT;
    float*       ob = out + (size_t)b * LTOT;

    float sig[CHUNK];

    for (int s = 0; s < NSEG; ++s) {
        const int p = s & 1, np = p ^ 1;

        const float4* src = reinterpret_cast<const float4*>(xb + (size_t)s * SEGLEN + (size_t)tid * CHUNK);
        #pragma unroll
        for (int i = 0; i < CHUNK / 4; ++i) {
            const float4 v = src[i];
            sig[4*i+0] = v.x; sig[4*i+1] = v.y; sig[4*i+2] = v.z; sig[4*i+3] = v.w;
        }
        bnd[tid] = make_float2(sig[31], sig[30]);
        if (tid == THREADS - 1) sxs[np] = make_float2(sig[31], sig[30]);
        __syncthreads();

        float xw1, xw2;   // raw-x window for section 0's FIR-A
        {
            const float2 t0 = (tid == 0) ? sxs[p] : bnd[tid - 1];
            xw1 = t0.x; xw2 = t0.y;
        }
        float i1 = 0.f, i2 = 0.f, i3 = 0.f, i4 = 0.f;  // true s_in of pair j (set by scan)

        for (int j = 0; j < NSEC; ++j) {
            const int buf = j & 1;
            const float* cj = wsb + j*32;
            const float b0A = cj[0], b1A = cj[1], b2A = cj[2], a1A = cj[3], a2A = cj[4];
            const float b0B = cj[5], b1B = cj[6], b2B = cj[7], a1B = cj[8], a2B = cj[9];
            const float* mb = wsb + MATS_OFF + j*11*16;

            // ---- fused: finalize pair j-1 + FIR-A_j + zero-init pair j ----
            float zA1 = 0.f, zA2 = 0.f, zB1 = 0.f, zB2 = 0.f;
            if (j == 0) {
                float u1 = xw1, u2 = xw2;
                #pragma unroll
                for (int t = 0; t < CHUNK; ++t) {
                    const float u   = sig[t];
                    const float cA  = b0A*u + b1A*u1 + b2A*u2;
                    const float zA  = cA - a1A*zA1 - a2A*zA2;
                    const float czB = b0B*zA + b1B*zA1 + b2B*zA2;
                    const float zB  = czB - a1B*zB1 - a2B*zB2;
                    sig[t] = cA;
                    u2 = u1; u1 = u;
                    zA2 = zA1; zA1 = zA; zB2 = zB1; zB1 = zB;
                }
            } else {
                const float* cp = wsb + (j-1)*32;
                const float pa1A = cp[3], pa2A = cp[4];
                const float pb0B = cp[5], pb1B = cp[6], pb2B = cp[7];
                const float pa1B = cp[8], pa2B = cp[9];
                float vA1 = i1, vA2 = i2, vB1 = i3, vB2 = i4;
                #pragma unroll
                for (int t = 0; t < CHUNK; ++t) {
                    const float cAp = sig[t];                          // stored FIR-A of pair j-1
                    const float vA  = cAp - pa1A*vA1 - pa2A*vA2;       // finalize A
                    const float cB  = pb0B*vA + pb1B*vA1 + pb2B*vA2;   // FIR-B (true vA window)
                    const float vB  = cB - pa1B*vB1 - pa2B*vB2;        // finalize B = true input u_t
                    const float cA  = b0A*vB + b1A*vB1 + b2A*vB2;      // FIR-A_j (u-window == vB-window)
                    const float zA  = cA - a1A*zA1 - a2A*zA2;
                    const float czB = b0B*zA + b1B*zA1 + b2B*zA2;
                    const float zB  = czB - a1B*zB1 - a2B*zB2;
                    sig[t] = cA;
                    vA2 = vA1; vA1 = vA; vB2 = vB1; vB1 = vB;
                    zA2 = zA1; zA1 = zA; zB2 = zB1; zB1 = zB;
                }
            }

            // ---- in-wave inclusive affine scan of p = (zA1,zA2,zB1,zB2) ----
            float Sx = zA1, Sy_ = zA2, Sz = zB1, Sw = zB2;
            #pragma unroll
            for (int r = 0; r < 6; ++r) {
                const int d = 1 << r;
                const float4* mp = reinterpret_cast<const float4*>(mb + r*16);
                const float4 r0 = mp[0], r1 = mp[1], r2 = mp[2], r3 = mp[3];
                float tx = __shfl_up(Sx, d, 64), ty = __shfl_up(Sy_, d, 64),
                      tz = __shfl_up(Sz, d, 64), tw = __shfl_up(Sw, d, 64);
                const bool act = (lane >= d);
                tx = act ? tx : 0.f; ty = act ? ty : 0.f;
                tz = act ? tz : 0.f; tw = act ? tw : 0.f;
                mva4(r0, r1, r2, r3, tx, ty, tz, tw, Sx, Sy_, Sz, Sw);
            }
            if (lane == 63) waveP[buf][wid] = make_float4(Sx, Sy_, Sz, Sw);
            __syncthreads();

            // ---- cross-wave: 4-level scan over 16 wave totals + carry ----
            const float4 sv = sy[p][j];
            const float4 Pv = waveP[buf][lane & 15];
            float Tx = Pv.x, Ty = Pv.y, Tz = Pv.z, Tw = Pv.w;
            float Vx = sv.x, Vy = sv.y, Vz = sv.z, Vw = sv.w;
            #pragma unroll
            for (int l = 0; l < 4; ++l) {
                const float4* mp = reinterpret_cast<const float4*>(mb + (6+l)*16);
                const float4 r0 = mp[0], r1 = mp[1], r2 = mp[2], r3 = mp[3];
                const int d = 1 << l;
                float tx = __shfl_up(Tx, d, 64), ty = __shfl_up(Ty, d, 64),
                      tz = __shfl_up(Tz, d, 64), tw = __shfl_up(Tw, d, 64);
                const bool act = (lane >= d);
                tx = act ? tx : 0.f; ty = act ? ty : 0.f;
                tz = act ? tz : 0.f; tw = act ? tw : 0.f;
                mva4(r0, r1, r2, r3, tx, ty, tz, tw, Tx, Ty, Tz, Tw);
                if ((wid >> l) & 1) {          // wave-uniform branch
                    float nx, ny, nz, nw;
                    mv4(r0, r1, r2, r3, Vx, Vy, Vz, Vw, nx, ny, nz, nw);
                    Vx = nx; Vy = ny; Vz = nz; Vw = nw;
                }
            }
            if (tid == 15) {   // lane 15 of wave 0: full-segment particular total
                const float4* mp = reinterpret_cast<const float4*>(mb + 10*16);
                float nx, ny, nz, nw;
                mv4(mp[0], mp[1], mp[2], mp[3], sv.x, sv.y, sv.z, sv.w, nx, ny, nz, nw);
                sy[np][j] = make_float4(nx + Tx, ny + Ty, nz + Tz, nw + Tw);
            }
            {   // V = M^(2048*wid)*sv + Q_{wid-1}
                const int srcl = wid - 1;
                float tx = __shfl(Tx, srcl, 64), ty = __shfl(Ty, srcl, 64),
                      tz = __shfl(Tz, srcl, 64), tw = __shfl(Tw, srcl, 64);
                const bool nz0 = (wid != 0);
                Vx += nz0 ? tx : 0.f; Vy += nz0 ? ty : 0.f;
                Vz += nz0 ? tz : 0.f; Vw += nz0 ? tw : 0.f;
            }
            #pragma unroll
            for (int r = 0; r < 6; ++r) {      // V = M^(32*lane) * V
                const float4* mp = reinterpret_cast<const float4*>(mb + r*16);
                const float4 r0 = mp[0], r1 = mp[1], r2 = mp[2], r3 = mp[3];
                const bool bit = (lane >> r) & 1;
                float nx, ny, nz, nw;
                mv4(r0, r1, r2, r3, Vx, Vy, Vz, Vw, nx, ny, nz, nw);
                Vx = bit ? nx : Vx; Vy = bit ? ny : Vy;
                Vz = bit ? nz : Vz; Vw = bit ? nw : Vw;
            }
            {   // + exclusive in-wave particular prefix
                float tx = __shfl_up(Sx, 1, 64), ty = __shfl_up(Sy_, 1, 64),
                      tz = __shfl_up(Sz, 1, 64), tw = __shfl_up(Sw, 1, 64);
                const bool l0 = (lane == 0);
                i1 = Vx + (l0 ? 0.f : tx);
                i2 = Vy + (l0 ? 0.f : ty);
                i3 = Vz + (l0 ? 0.f : tz);
                i4 = Vw + (l0 ? 0.f : tw);
            }
        }

        // ---- tail: finalize pair 4 + vectorized store ----
        {
            const float* cp = wsb + (NSEC-1)*32;
            const float pa1A = cp[3], pa2A = cp[4];
            const float pb0B = cp[5], pb1B = cp[6], pb2B = cp[7];
            const float pa1B = cp[8], pa2B = cp[9];
            float vA1 = i1, vA2 = i2, vB1 = i3, vB2 = i4;
            float4* dst = reinterpret_cast<float4*>(ob + (size_t)s * SEGLEN + (size_t)tid * CHUNK);
            #pragma unroll
            for (int i = 0; i < CHUNK / 4; ++i) {
                float4 o;
                #pragma unroll
                for (int e = 0; e < 4; ++e) {
                    const float vA = sig[4*i+e] - pa1A*vA1 - pa2A*vA2;
                    const float cB = pb0B*vA + pb1B*vA1 + pb2B*vA2;
                    const float vB = cB - pa1B*vB1 - pa2B*vB2;
                    (&o.x)[e] = vB;
                    vA2 = vA1; vA1 = vA; vB2 = vB1; vB1 = vB;
                }
                dst[i] = o;
            }
        }
    }
}

extern "C" void kernel_launch(void* const* d_in, const int* in_sizes, int n_in,
                              void* d_out, int out_size, void* d_ws, size_t ws_size,
                              hipStream_t stream) {
    const float* x    = (const float*)d_in[0];
    const float* w0   = (const float*)d_in[1];
    const float* qinv = (const float*)d_in[2];
    const float* gain = (const float*)d_in[3];
    float* out = (float*)d_out;
    float* ws  = (float*)d_ws;   // needs 256 * 4.5 KiB = 1.125 MiB

    const int B = in_sizes[1] / NFILT;   // 256 batches (C=1 folded in)
    eq_precompute_kernel<<<B, 64, 0, stream>>>(w0, qinv, gain, ws);
    eq_cascade_kernel<<<B, THREADS, 0, stream>>>(x, out, ws);
}

// Round 9
// 120.636 us; speedup vs baseline: 1.0622x; 1.0622x over previous
//
#include <hip/hip_runtime.h>
#include <math.h>

#ifndef M_PI
#define M_PI 3.14159265358979323846
#endif

#define NFILT   10
#define THREADS 1024
#define CHUNK   64                  // one chunk per thread, whole signal in one segment
#define LTOT    (THREADS * CHUNK)   // 65536
#define NWAVE   (THREADS / 64)      // 16

#define WS_STRIDE 576               // floats per batch
#define MATS_OFF  96                // coefs: j*8 (j<10); matrices after: (j*10+r)*4

// ---------------- precompute (f64) ----------------

__device__ inline void biquad_coefs(int k, double w0r, double qir, double gr,
                                    double* bo, double* ao) {
    const double w0 = M_PI / (1.0 + exp(-w0r));
    const double qi = exp(qir);
    const double A  = exp(gr);
    const double cw = cos(w0);
    const double al = sin(w0) * qi * 0.5;
    double B0, B1, B2, A0, A1, A2;
    if (k == 0) {                       // low shelf
        const double Ap1 = A + 1.0, Am1 = A - 1.0, tsa = 2.0 * sqrt(A) * al;
        B0 = A * (Ap1 - Am1 * cw + tsa);
        B1 = 2.0 * A * (Am1 - Ap1 * cw);
        B2 = A * (Ap1 - Am1 * cw - tsa);
        A0 = Ap1 + Am1 * cw + tsa;
        A1 = -2.0 * (Am1 + Ap1 * cw);
        A2 = Ap1 + Am1 * cw - tsa;
    } else if (k == NFILT - 1) {        // high shelf
        const double Ap1 = A + 1.0, Am1 = A - 1.0, tsa = 2.0 * sqrt(A) * al;
        B0 = A * (Ap1 + Am1 * cw + tsa);
        B1 = -2.0 * A * (Am1 + Ap1 * cw);
        B2 = A * (Ap1 + Am1 * cw - tsa);
        A0 = Ap1 - Am1 * cw + tsa;
        A1 = 2.0 * (Am1 - Ap1 * cw);
        A2 = Ap1 - Am1 * cw - tsa;
    } else {                            // peaking
        const double aA = al * A, aiA = al / A;
        B0 = 1.0 + aA;  B1 = -2.0 * cw; B2 = 1.0 - aA;
        A0 = 1.0 + aiA; A1 = B1;        A2 = 1.0 - aiA;
    }
    const double inv = 1.0 / A0;
    bo[0] = B0 * inv; bo[1] = B1 * inv; bo[2] = B2 * inv;
    ao[0] = 1.0;      ao[1] = A1 * inv; ao[2] = A2 * inv;
}

// Per batch b, filter j: normalized coefs + companion-matrix powers
// C^(64*2^r), r=0..9 (C = [[-a1,-a2],[1,0]], state (y_{t-1}, y_{t-2})).
__global__ void eq_precompute_kernel(const float* __restrict__ w0_in,
                                     const float* __restrict__ qinv_in,
                                     const float* __restrict__ gain_in,
                                     float* __restrict__ ws)
{
    const int b = blockIdx.x;
    const int j = threadIdx.x;
    if (j >= NFILT) return;

    double bo[3], ao[3];
    biquad_coefs(j, (double)w0_in[b*NFILT+j], (double)qinv_in[b*NFILT+j],
                 (double)gain_in[b*NFILT+j], bo, ao);

    float* wb = ws + (size_t)b * WS_STRIDE;
    float* cj = wb + j * 8;
    cj[0] = (float)bo[0]; cj[1] = (float)bo[1]; cj[2] = (float)bo[2];
    cj[3] = (float)ao[1]; cj[4] = (float)ao[2];

    double m0 = -ao[1], m1 = -ao[2], m2 = 1.0, m3 = 0.0;   // C
    #pragma unroll
    for (int i = 0; i < 6; ++i) {                          // -> C^64
        const double n0 = m0*m0 + m1*m2, n1 = m0*m1 + m1*m3;
        const double n2 = m2*m0 + m3*m2, n3 = m2*m1 + m3*m3;
        m0 = n0; m1 = n1; m2 = n2; m3 = n3;
    }
    for (int r = 0; r < 10; ++r) {                         // C^(64*2^r)
        float* mr = wb + MATS_OFF + (j*10 + r)*4;
        mr[0] = (float)m0; mr[1] = (float)m1; mr[2] = (float)m2; mr[3] = (float)m3;
        const double n0 = m0*m0 + m1*m2, n1 = m0*m1 + m1*m3;
        const double n2 = m2*m0 + m3*m2, n3 = m2*m1 + m3*m3;
        m0 = n0; m1 = n1; m2 = n2; m3 = n3;
    }
}

// ---------------- main kernel ----------------

__global__ void
__attribute__((amdgpu_flat_work_group_size(THREADS, THREADS)))
__attribute__((amdgpu_waves_per_eu(4, 4)))
eq_cascade_kernel(const float* __restrict__ x,
                  float* __restrict__ out,
                  const float* __restrict__ ws)
{
    __shared__ float2 bnd[THREADS];      // raw-x chunk boundary (x_{-1}, x_{-2})
    __shared__ float2 waveP[2][NWAVE];   // per-wave inclusive particular totals

    const int tid  = threadIdx.x;
    const int lane = tid & 63;
    const int wid  = tid >> 6;
    const int b    = blockIdx.x;
    const float* __restrict__ wsb = ws + (size_t)b * WS_STRIDE;

    const float* xb = x   + (size_t)b * LTOT;
    float*       ob = out + (size_t)b * LTOT;

    float sig[CHUNK];

    // ---- load one 64-sample chunk per thread ----
    const float4* src = reinterpret_cast<const float4*>(xb + (size_t)tid * CHUNK);
    #pragma unroll
    for (int i = 0; i < CHUNK / 4; ++i) {
        const float4 v = src[i];
        sig[4*i+0] = v.x; sig[4*i+1] = v.y; sig[4*i+2] = v.z; sig[4*i+3] = v.w;
    }
    bnd[tid] = make_float2(sig[CHUNK-1], sig[CHUNK-2]);
    __syncthreads();

    float xw1, xw2;   // raw-x history at chunk start (zeros for tid 0)
    {
        const float2 t0 = (tid == 0) ? make_float2(0.f, 0.f) : bnd[tid - 1];
        xw1 = t0.x; xw2 = t0.y;
    }
    float i1 = 0.f, i2 = 0.f;     // true output state of current filter at chunk start
    float pa1 = 0.f, pa2 = 0.f;   // previous filter's a-coefs

    #pragma unroll 1
    for (int j = 0; j < NFILT; ++j) {
        const float* cj = wsb + j*8;
        const float b0 = cj[0], b1c = cj[1], b2 = cj[2], a1 = cj[3], a2 = cj[4];
        const float* mb = wsb + MATS_OFF + j*40;

        // ---- fused: finalize(j-1) + FIR(j) + zero-init recurrence(j) ----
        float z1 = 0.f, z2 = 0.f;
        if (j == 0) {
            float u1 = xw1, u2 = xw2;
            #pragma unroll
            for (int t = 0; t < CHUNK; ++t) {
                const float u = sig[t];
                const float c = b0*u + b1c*u1 + b2*u2;
                const float z = c - a1*z1 - a2*z2;
                sig[t] = c;
                u2 = u1; u1 = u;
                z2 = z1; z1 = z;
            }
        } else {
            float u1 = i1, u2 = i2;
            #pragma unroll
            for (int t = 0; t < CHUNK; ++t) {
                const float u = sig[t] - pa1*u1 - pa2*u2;   // finalize prev filter
                const float c = b0*u + b1c*u1 + b2*u2;      // FIR of filter j
                const float z = c - a1*z1 - a2*z2;          // zero-init recurrence
                sig[t] = c;
                u2 = u1; u1 = u;
                z2 = z1; z1 = z;
            }
        }

        // ---- in-wave inclusive affine scan of (z1, z2) ----
        float Sa = z1, Sb = z2;
        #pragma unroll
        for (int r = 0; r < 6; ++r) {
            const int d = 1 << r;
            const float4 M = *reinterpret_cast<const float4*>(mb + r*4);
            float ta = __shfl_up(Sa, d, 64);
            float tb = __shfl_up(Sb, d, 64);
            const bool act = (lane >= d);
            ta = act ? ta : 0.f;
            tb = act ? tb : 0.f;
            Sa = Sa + M.x * ta + M.y * tb;
            Sb = Sb + M.z * ta + M.w * tb;
        }
        const int buf = j & 1;
        if (lane == 63) waveP[buf][wid] = make_float2(Sa, Sb);
        __syncthreads();

        // ---- cross-wave: 4-level KS over 16 wave totals (in lane space) ----
        const float2 Pv = waveP[buf][lane & 15];
        float Tx = Pv.x, Ty = Pv.y;
        #pragma unroll
        for (int l = 0; l < 4; ++l) {
            const int d = 1 << l;
            const float4 M = *reinterpret_cast<const float4*>(mb + (6+l)*4);
            float tx = __shfl_up(Tx, d, 64);
            float ty = __shfl_up(Ty, d, 64);
            const bool act = (lane >= d);
            tx = act ? tx : 0.f;
            ty = act ? ty : 0.f;
            Tx = Tx + M.x * tx + M.y * ty;
            Ty = Ty + M.z * tx + M.w * ty;
        }
        // wave-incoming state V = T_{wid-1} (zero state at signal start)
        float Vx = __shfl(Tx, wid - 1, 64);
        float Vy = __shfl(Ty, wid - 1, 64);
        if (wid == 0) { Vx = 0.f; Vy = 0.f; }
        // apply C^(64*lane)
        #pragma unroll
        for (int r = 0; r < 6; ++r) {
            const float4 M = *reinterpret_cast<const float4*>(mb + r*4);
            const bool bit = (lane >> r) & 1;
            const float nx = M.x * Vx + M.y * Vy;
            const float ny = M.z * Vx + M.w * Vy;
            Vx = bit ? nx : Vx;
            Vy = bit ? ny : Vy;
        }
        // + exclusive in-wave particular prefix
        {
            float Ea = __shfl_up(Sa, 1, 64);
            float Eb = __shfl_up(Sb, 1, 64);
            const bool l0 = (lane == 0);
            i1 = Vx + (l0 ? 0.f : Ea);
            i2 = Vy + (l0 ? 0.f : Eb);
        }
        pa1 = a1; pa2 = a2;
    }

    // ---- tail: finalize filter 9 + vectorized store ----
    {
        float y1 = i1, y2 = i2;
        float4* dst = reinterpret_cast<float4*>(ob + (size_t)tid * CHUNK);
        #pragma unroll
        for (int i = 0; i < CHUNK / 4; ++i) {
            float4 o;
            o.x = sig[4*i+0] - pa1*y1 - pa2*y2; y2 = y1; y1 = o.x;
            o.y = sig[4*i+1] - pa1*y1 - pa2*y2; y2 = y1; y1 = o.y;
            o.z = sig[4*i+2] - pa1*y1 - pa2*y2; y2 = y1; y1 = o.z;
            o.w = sig[4*i+3] - pa1*y1 - pa2*y2; y2 = y1; y1 = o.w;
            dst[i] = o;
        }
    }
}

extern "C" void kernel_launch(void* const* d_in, const int* in_sizes, int n_in,
                              void* d_out, int out_size, void* d_ws, size_t ws_size,
                              hipStream_t stream) {
    const float* x    = (const float*)d_in[0];
    const float* w0   = (const float*)d_in[1];
    const float* qinv = (const float*)d_in[2];
    const float* gain = (const float*)d_in[3];
    float* out = (float*)d_out;
    float* ws  = (float*)d_ws;   // needs 256 * 576 * 4 B = 576 KiB

    const int B = in_sizes[1] / NFILT;   // 256 batches (C=1 folded in)
    eq_precompute_kernel<<<B, 64, 0, stream>>>(w0, qinv, gain, ws);
    eq_cascade_kernel<<<B, THREADS, 0, stream>>>(x, out, ws);
}

// Round 10
// 100.295 us; speedup vs baseline: 1.2776x; 1.2028x over previous
//
#include <hip/hip_runtime.h>
#include <math.h>

#ifndef M_PI
#define M_PI 3.14159265358979323846
#endif

#define NFILT   10
#define THREADS 1024
#define CHUNK   64                  // 32 samples in VGPRs + 32 samples in LDS
#define REGS    32                  // register-resident samples per thread
#define LDSS    (CHUNK - REGS)      // LDS-resident samples per thread
#define LTOT    (THREADS * CHUNK)   // 65536
#define NWAVE   (THREADS / 64)      // 16

#define WS_STRIDE 576               // floats per batch
#define MATS_OFF  96                // coefs: j*8 (j<10); matrices: (j*10+r)*4

// ---------------- precompute (f64) ----------------

__device__ inline void biquad_coefs(int k, double w0r, double qir, double gr,
                                    double* bo, double* ao) {
    const double w0 = M_PI / (1.0 + exp(-w0r));
    const double qi = exp(qir);
    const double A  = exp(gr);
    const double cw = cos(w0);
    const double al = sin(w0) * qi * 0.5;
    double B0, B1, B2, A0, A1, A2;
    if (k == 0) {                       // low shelf
        const double Ap1 = A + 1.0, Am1 = A - 1.0, tsa = 2.0 * sqrt(A) * al;
        B0 = A * (Ap1 - Am1 * cw + tsa);
        B1 = 2.0 * A * (Am1 - Ap1 * cw);
        B2 = A * (Ap1 - Am1 * cw - tsa);
        A0 = Ap1 + Am1 * cw + tsa;
        A1 = -2.0 * (Am1 + Ap1 * cw);
        A2 = Ap1 + Am1 * cw - tsa;
    } else if (k == NFILT - 1) {        // high shelf
        const double Ap1 = A + 1.0, Am1 = A - 1.0, tsa = 2.0 * sqrt(A) * al;
        B0 = A * (Ap1 + Am1 * cw + tsa);
        B1 = -2.0 * A * (Am1 + Ap1 * cw);
        B2 = A * (Ap1 + Am1 * cw - tsa);
        A0 = Ap1 - Am1 * cw + tsa;
        A1 = 2.0 * (Am1 - Ap1 * cw);
        A2 = Ap1 - Am1 * cw - tsa;
    } else {                            // peaking
        const double aA = al * A, aiA = al / A;
        B0 = 1.0 + aA;  B1 = -2.0 * cw; B2 = 1.0 - aA;
        A0 = 1.0 + aiA; A1 = B1;        A2 = 1.0 - aiA;
    }
    const double inv = 1.0 / A0;
    bo[0] = B0 * inv; bo[1] = B1 * inv; bo[2] = B2 * inv;
    ao[0] = 1.0;      ao[1] = A1 * inv; ao[2] = A2 * inv;
}

// Per batch b, filter j: normalized coefs + companion-matrix powers
// C^(64*2^r), r=0..9 (C = [[-a1,-a2],[1,0]], state (y_{t-1}, y_{t-2})).
__global__ void eq_precompute_kernel(const float* __restrict__ w0_in,
                                     const float* __restrict__ qinv_in,
                                     const float* __restrict__ gain_in,
                                     float* __restrict__ ws)
{
    const int b = blockIdx.x;
    const int j = threadIdx.x;
    if (j >= NFILT) return;

    double bo[3], ao[3];
    biquad_coefs(j, (double)w0_in[b*NFILT+j], (double)qinv_in[b*NFILT+j],
                 (double)gain_in[b*NFILT+j], bo, ao);

    float* wb = ws + (size_t)b * WS_STRIDE;
    float* cj = wb + j * 8;
    cj[0] = (float)bo[0]; cj[1] = (float)bo[1]; cj[2] = (float)bo[2];
    cj[3] = (float)ao[1]; cj[4] = (float)ao[2];

    double m0 = -ao[1], m1 = -ao[2], m2 = 1.0, m3 = 0.0;   // C
    #pragma unroll
    for (int i = 0; i < 6; ++i) {                          // -> C^64
        const double n0 = m0*m0 + m1*m2, n1 = m0*m1 + m1*m3;
        const double n2 = m2*m0 + m3*m2, n3 = m2*m1 + m3*m3;
        m0 = n0; m1 = n1; m2 = n2; m3 = n3;
    }
    for (int r = 0; r < 10; ++r) {                         // C^(64*2^r)
        float* mr = wb + MATS_OFF + (j*10 + r)*4;
        mr[0] = (float)m0; mr[1] = (float)m1; mr[2] = (float)m2; mr[3] = (float)m3;
        const double n0 = m0*m0 + m1*m2, n1 = m0*m1 + m1*m3;
        const double n2 = m2*m0 + m3*m2, n3 = m2*m1 + m3*m3;
        m0 = n0; m1 = n1; m2 = n2; m3 = n3;
    }
}

// ---------------- main kernel ----------------

__global__ void
__attribute__((amdgpu_flat_work_group_size(THREADS, THREADS)))
__attribute__((amdgpu_waves_per_eu(4, 4)))
eq_cascade_kernel(const float* __restrict__ x,
                  float* __restrict__ out,
                  const float* __restrict__ ws)
{
    __shared__ float4 sigh[LDSS/4][THREADS];   // samples 32..63, 128 KiB, thread-private
    __shared__ float2 bnd[THREADS];            // raw-x chunk boundary (x_{-1}, x_{-2})
    __shared__ float2 waveP[2][NWAVE];         // per-wave inclusive particular totals

    const int tid  = threadIdx.x;
    const int lane = tid & 63;
    const int wid  = tid >> 6;
    const int b    = blockIdx.x;
    const float* __restrict__ wsb = ws + (size_t)b * WS_STRIDE;

    const float* xb = x   + (size_t)b * LTOT;
    float*       ob = out + (size_t)b * LTOT;

    float sig[REGS];

    // ---- load 64 samples: first 32 -> regs, last 32 -> LDS ----
    const float4* src = reinterpret_cast<const float4*>(xb + (size_t)tid * CHUNK);
    #pragma unroll
    for (int i = 0; i < REGS/4; ++i) {
        const float4 v = src[i];
        sig[4*i+0] = v.x; sig[4*i+1] = v.y; sig[4*i+2] = v.z; sig[4*i+3] = v.w;
    }
    float4 vlast;
    #pragma unroll
    for (int i = 0; i < LDSS/4; ++i) {
        const float4 v = src[REGS/4 + i];
        sigh[i][tid] = v;
        if (i == LDSS/4 - 1) vlast = v;
    }
    bnd[tid] = make_float2(vlast.w, vlast.z);
    __syncthreads();

    float xw1, xw2;   // raw-x history at chunk start (zeros for tid 0)
    {
        const float2 t0 = (tid == 0) ? make_float2(0.f, 0.f) : bnd[tid - 1];
        xw1 = t0.x; xw2 = t0.y;
    }
    float i1 = 0.f, i2 = 0.f;     // true output state of current filter at chunk start
    float pa1 = 0.f, pa2 = 0.f;   // previous filter's a-coefs

    #pragma unroll 1
    for (int j = 0; j < NFILT; ++j) {
        const float* cj = wsb + j*8;
        const float b0 = cj[0], b1c = cj[1], b2 = cj[2], a1 = cj[3], a2 = cj[4];
        const float* mb = wsb + MATS_OFF + j*40;

        // ---- fused: finalize(j-1) + FIR(j) + zero-init recurrence(j) ----
        float z1 = 0.f, z2 = 0.f;
        float u1, u2;
        if (j == 0) {
            u1 = xw1; u2 = xw2;
            #pragma unroll
            for (int t = 0; t < REGS; ++t) {
                const float u = sig[t];
                const float c = b0*u + b1c*u1 + b2*u2;
                const float z = c - a1*z1 - a2*z2;
                sig[t] = c;
                u2 = u1; u1 = u;
                z2 = z1; z1 = z;
            }
            #pragma unroll
            for (int i = 0; i < LDSS/4; ++i) {
                const float4 v = sigh[i][tid];
                float4 r;
                #pragma unroll
                for (int e = 0; e < 4; ++e) {
                    const float u = (&v.x)[e];
                    const float c = b0*u + b1c*u1 + b2*u2;
                    const float z = c - a1*z1 - a2*z2;
                    (&r.x)[e] = c;
                    u2 = u1; u1 = u;
                    z2 = z1; z1 = z;
                }
                sigh[i][tid] = r;
            }
        } else {
            u1 = i1; u2 = i2;
            #pragma unroll
            for (int t = 0; t < REGS; ++t) {
                const float u = sig[t] - pa1*u1 - pa2*u2;   // finalize prev filter
                const float c = b0*u + b1c*u1 + b2*u2;      // FIR of filter j
                const float z = c - a1*z1 - a2*z2;          // zero-init recurrence
                sig[t] = c;
                u2 = u1; u1 = u;
                z2 = z1; z1 = z;
            }
            #pragma unroll
            for (int i = 0; i < LDSS/4; ++i) {
                const float4 v = sigh[i][tid];
                float4 r;
                #pragma unroll
                for (int e = 0; e < 4; ++e) {
                    const float u = (&v.x)[e] - pa1*u1 - pa2*u2;
                    const float c = b0*u + b1c*u1 + b2*u2;
                    const float z = c - a1*z1 - a2*z2;
                    (&r.x)[e] = c;
                    u2 = u1; u1 = u;
                    z2 = z1; z1 = z;
                }
                sigh[i][tid] = r;
            }
        }

        // ---- in-wave inclusive affine scan of (z1, z2) ----
        float Sa = z1, Sb = z2;
        #pragma unroll
        for (int r = 0; r < 6; ++r) {
            const int d = 1 << r;
            const float4 M = *reinterpret_cast<const float4*>(mb + r*4);
            float ta = __shfl_up(Sa, d, 64);
            float tb = __shfl_up(Sb, d, 64);
            const bool act = (lane >= d);
            ta = act ? ta : 0.f;
            tb = act ? tb : 0.f;
            Sa = Sa + M.x * ta + M.y * tb;
            Sb = Sb + M.z * ta + M.w * tb;
        }
        const int buf = j & 1;
        if (lane == 63) waveP[buf][wid] = make_float2(Sa, Sb);
        __syncthreads();

        // ---- cross-wave: 4-level KS over 16 wave totals (in lane space) ----
        const float2 Pv = waveP[buf][lane & 15];
        float Tx = Pv.x, Ty = Pv.y;
        #pragma unroll
        for (int l = 0; l < 4; ++l) {
            const int d = 1 << l;
            const float4 M = *reinterpret_cast<const float4*>(mb + (6+l)*4);
            float tx = __shfl_up(Tx, d, 64);
            float ty = __shfl_up(Ty, d, 64);
            const bool act = (lane >= d);
            tx = act ? tx : 0.f;
            ty = act ? ty : 0.f;
            Tx = Tx + M.x * tx + M.y * ty;
            Ty = Ty + M.z * tx + M.w * ty;
        }
        // wave-incoming state V = T_{wid-1} (zero state at signal start)
        float Vx = __shfl(Tx, wid - 1, 64);
        float Vy = __shfl(Ty, wid - 1, 64);
        if (wid == 0) { Vx = 0.f; Vy = 0.f; }
        // apply C^(64*lane)
        #pragma unroll
        for (int r = 0; r < 6; ++r) {
            const float4 M = *reinterpret_cast<const float4*>(mb + r*4);
            const bool bit = (lane >> r) & 1;
            const float nx = M.x * Vx + M.y * Vy;
            const float ny = M.z * Vx + M.w * Vy;
            Vx = bit ? nx : Vx;
            Vy = bit ? ny : Vy;
        }
        // + exclusive in-wave particular prefix
        {
            float Ea = __shfl_up(Sa, 1, 64);
            float Eb = __shfl_up(Sb, 1, 64);
            const bool l0 = (lane == 0);
            i1 = Vx + (l0 ? 0.f : Ea);
            i2 = Vy + (l0 ? 0.f : Eb);
        }
        pa1 = a1; pa2 = a2;
    }

    // ---- tail: finalize filter 9 + vectorized store ----
    {
        float y1 = i1, y2 = i2;
        float4* dst = reinterpret_cast<float4*>(ob + (size_t)tid * CHUNK);
        #pragma unroll
        for (int i = 0; i < REGS/4; ++i) {
            float4 o;
            o.x = sig[4*i+0] - pa1*y1 - pa2*y2; y2 = y1; y1 = o.x;
            o.y = sig[4*i+1] - pa1*y1 - pa2*y2; y2 = y1; y1 = o.y;
            o.z = sig[4*i+2] - pa1*y1 - pa2*y2; y2 = y1; y1 = o.z;
            o.w = sig[4*i+3] - pa1*y1 - pa2*y2; y2 = y1; y1 = o.w;
            dst[i] = o;
        }
        #pragma unroll
        for (int i = 0; i < LDSS/4; ++i) {
            const float4 v = sigh[i][tid];
            float4 o;
            o.x = v.x - pa1*y1 - pa2*y2; y2 = y1; y1 = o.x;
            o.y = v.y - pa1*y1 - pa2*y2; y2 = y1; y1 = o.y;
            o.z = v.z - pa1*y1 - pa2*y2; y2 = y1; y1 = o.z;
            o.w = v.w - pa1*y1 - pa2*y2; y2 = y1; y1 = o.w;
            dst[REGS/4 + i] = o;
        }
    }
}

extern "C" void kernel_launch(void* const* d_in, const int* in_sizes, int n_in,
                              void* d_out, int out_size, void* d_ws, size_t ws_size,
                              hipStream_t stream) {
    const float* x    = (const float*)d_in[0];
    const float* w0   = (const float*)d_in[1];
    const float* qinv = (const float*)d_in[2];
    const float* gain = (const float*)d_in[3];
    float* out = (float*)d_out;
    float* ws  = (float*)d_ws;   // needs 256 * 576 * 4 B = 576 KiB

    const int B = in_sizes[1] / NFILT;   // 256 batches (C=1 folded in)
    eq_precompute_kernel<<<B, 64, 0, stream>>>(w0, qinv, gain, ws);
    eq_cascade_kernel<<<B, THREADS, 0, stream>>>(x, out, ws);
}

// Round 11
// 79.930 us; speedup vs baseline: 1.6031x; 1.2548x over previous
//
#include <hip/hip_runtime.h>
#include <math.h>

#ifndef M_PI
#define M_PI 3.14159265358979323846
#endif

#define NFILT   10
#define THREADS 1024
#define CHUNK   64                  // 32 samples in VGPRs + 32 samples in LDS
#define REGS    32
#define LDSS    (CHUNK - REGS)
#define LTOT    (THREADS * CHUNK)   // 65536
#define NWAVE   (THREADS / 64)      // 16

#define WS_STRIDE 576               // floats per batch
#define MATS_OFF  96                // coefs: j*8; matrices: (j*10+r)*4

typedef float v2f __attribute__((ext_vector_type(2)));
__device__ inline v2f mk2(float a, float b) { v2f r; r.x = a; r.y = b; return r; }
#define F2(a,b,c) __builtin_elementwise_fma((a),(b),(c))

// ---------------- precompute (f64) ----------------

__device__ inline void biquad_coefs(int k, double w0r, double qir, double gr,
                                    double* bo, double* ao) {
    const double w0 = M_PI / (1.0 + exp(-w0r));
    const double qi = exp(qir);
    const double A  = exp(gr);
    const double cw = cos(w0);
    const double al = sin(w0) * qi * 0.5;
    double B0, B1, B2, A0, A1, A2;
    if (k == 0) {
        const double Ap1 = A + 1.0, Am1 = A - 1.0, tsa = 2.0 * sqrt(A) * al;
        B0 = A * (Ap1 - Am1 * cw + tsa);
        B1 = 2.0 * A * (Am1 - Ap1 * cw);
        B2 = A * (Ap1 - Am1 * cw - tsa);
        A0 = Ap1 + Am1 * cw + tsa;
        A1 = -2.0 * (Am1 + Ap1 * cw);
        A2 = Ap1 + Am1 * cw - tsa;
    } else if (k == NFILT - 1) {
        const double Ap1 = A + 1.0, Am1 = A - 1.0, tsa = 2.0 * sqrt(A) * al;
        B0 = A * (Ap1 + Am1 * cw + tsa);
        B1 = -2.0 * A * (Am1 + Ap1 * cw);
        B2 = A * (Ap1 + Am1 * cw - tsa);
        A0 = Ap1 - Am1 * cw + tsa;
        A1 = 2.0 * (Am1 - Ap1 * cw);
        A2 = Ap1 - Am1 * cw - tsa;
    } else {
        const double aA = al * A, aiA = al / A;
        B0 = 1.0 + aA;  B1 = -2.0 * cw; B2 = 1.0 - aA;
        A0 = 1.0 + aiA; A1 = B1;        A2 = 1.0 - aiA;
    }
    const double inv = 1.0 / A0;
    bo[0] = B0 * inv; bo[1] = B1 * inv; bo[2] = B2 * inv;
    ao[0] = 1.0;      ao[1] = A1 * inv; ao[2] = A2 * inv;
}

// coefs per filter j: [b0,b1,b2,a1,a2, qa1=a1^2-a2, qa2=a1*a2, 0]
// matrices: C^(64*2^r), r=0..9, row-major (m0,m1,m2,m3)
__global__ void eq_precompute_kernel(const float* __restrict__ w0_in,
                                     const float* __restrict__ qinv_in,
                                     const float* __restrict__ gain_in,
                                     float* __restrict__ ws)
{
    const int b = blockIdx.x;
    const int j = threadIdx.x;
    if (j >= NFILT) return;

    double bo[3], ao[3];
    biquad_coefs(j, (double)w0_in[b*NFILT+j], (double)qinv_in[b*NFILT+j],
                 (double)gain_in[b*NFILT+j], bo, ao);

    float* wb = ws + (size_t)b * WS_STRIDE;
    float* cj = wb + j * 8;
    cj[0] = (float)bo[0]; cj[1] = (float)bo[1]; cj[2] = (float)bo[2];
    cj[3] = (float)ao[1]; cj[4] = (float)ao[2];
    cj[5] = (float)(ao[1]*ao[1] - ao[2]);   // qa1
    cj[6] = (float)(ao[1]*ao[2]);           // qa2

    double m0 = -ao[1], m1 = -ao[2], m2 = 1.0, m3 = 0.0;   // C
    #pragma unroll
    for (int i = 0; i < 6; ++i) {                          // -> C^64
        const double n0 = m0*m0 + m1*m2, n1 = m0*m1 + m1*m3;
        const double n2 = m2*m0 + m3*m2, n3 = m2*m1 + m3*m3;
        m0 = n0; m1 = n1; m2 = n2; m3 = n3;
    }
    for (int r = 0; r < 10; ++r) {                         // C^(64*2^r)
        float* mr = wb + MATS_OFF + (j*10 + r)*4;
        mr[0] = (float)m0; mr[1] = (float)m1; mr[2] = (float)m2; mr[3] = (float)m3;
        const double n0 = m0*m0 + m1*m2, n1 = m0*m1 + m1*m3;
        const double n2 = m2*m0 + m3*m2, n3 = m2*m1 + m3*m3;
        m0 = n0; m1 = n1; m2 = n2; m3 = n3;
    }
}

// ---------------- main kernel ----------------

__global__ void
__attribute__((amdgpu_flat_work_group_size(THREADS, THREADS)))
__attribute__((amdgpu_waves_per_eu(4, 4)))
eq_cascade_kernel(const float* __restrict__ x,
                  float* __restrict__ out,
                  const float* __restrict__ ws)
{
    __shared__ float4 sigh[LDSS/4][THREADS];   // samples 32..63 (thread-private)
    __shared__ float2 bnd[THREADS];
    __shared__ float2 waveP[2][NWAVE];

    const int tid  = threadIdx.x;
    const int lane = tid & 63;
    const int wid  = tid >> 6;
    const int b    = blockIdx.x;
    const float* __restrict__ wsb = ws + (size_t)b * WS_STRIDE;

    const float* xb = x   + (size_t)b * LTOT;
    float*       ob = out + (size_t)b * LTOT;

    float sig[REGS];

    // ---- load 64 samples: first 32 -> regs, last 32 -> LDS ----
    const float4* src = reinterpret_cast<const float4*>(xb + (size_t)tid * CHUNK);
    #pragma unroll
    for (int i = 0; i < REGS/4; ++i) {
        const float4 v = src[i];
        sig[4*i+0] = v.x; sig[4*i+1] = v.y; sig[4*i+2] = v.z; sig[4*i+3] = v.w;
    }
    float4 vlast;
    #pragma unroll
    for (int i = 0; i < LDSS/4; ++i) {
        const float4 v = src[REGS/4 + i];
        sigh[i][tid] = v;
        if (i == LDSS/4 - 1) vlast = v;
    }
    bnd[tid] = make_float2(vlast.w, vlast.z);
    __syncthreads();

    float xw1, xw2;
    {
        const float2 t0 = (tid == 0) ? make_float2(0.f, 0.f) : bnd[tid - 1];
        xw1 = t0.x; xw2 = t0.y;
    }
    float i1 = 0.f, i2 = 0.f;
    v2f PA0p = mk2(0.f, 0.f), PA1p = mk2(0.f, 0.f), PA2p = mk2(0.f, 0.f);

    #pragma unroll 1
    for (int j = 0; j < NFILT; ++j) {
        const float* cj = wsb + j*8;
        const float b0 = cj[0], b1c = cj[1], b2 = cj[2];
        const float a1 = cj[3], a2 = cj[4], qa1 = cj[5], qa2 = cj[6];
        const v2f B0v = mk2(b0, b0), B1v = mk2(b1c, b1c), B2v = mk2(b2, b2);
        const v2f A0v = mk2(0.f, -a1), A1v = mk2(-a1, qa1), A2v = mk2(-a2, qa2);
        const float* mb = wsb + MATS_OFF + j*40;

        // ---- fused packed: finalize(j-1) + FIR(j) + zero-init(j), pair-stepped ----
        v2f Zp = mk2(0.f, 0.f);
        v2f Up;
        if (j == 0) {
            Up = mk2(xw2, xw1);       // (u_{-2}, u_{-1}) = raw x history
            #pragma unroll
            for (int i = 0; i < REGS/2; ++i) {
                const v2f U  = mk2(sig[2*i], sig[2*i+1]);      // u = raw input
                const v2f M1 = mk2(Up.y, U.x);
                const v2f C  = F2(B2v, Up, F2(B1v, M1, B0v*U));
                const v2f Ch = F2(A0v, mk2(C.x, C.x), C);
                const v2f Z  = F2(A2v, mk2(Zp.x, Zp.x), F2(A1v, mk2(Zp.y, Zp.y), Ch));
                sig[2*i] = C.x; sig[2*i+1] = C.y;
                Up = U; Zp = Z;
            }
            #pragma unroll
            for (int i = 0; i < LDSS/4; ++i) {
                const float4 v = sigh[i][tid];
                float4 r;
                #pragma unroll
                for (int h = 0; h < 2; ++h) {
                    const v2f U  = (h == 0) ? mk2(v.x, v.y) : mk2(v.z, v.w);
                    const v2f M1 = mk2(Up.y, U.x);
                    const v2f C  = F2(B2v, Up, F2(B1v, M1, B0v*U));
                    const v2f Ch = F2(A0v, mk2(C.x, C.x), C);
                    const v2f Z  = F2(A2v, mk2(Zp.x, Zp.x), F2(A1v, mk2(Zp.y, Zp.y), Ch));
                    if (h == 0) { r.x = C.x; r.y = C.y; } else { r.z = C.x; r.w = C.y; }
                    Up = U; Zp = Z;
                }
                sigh[i][tid] = r;
            }
        } else {
            Up = mk2(i2, i1);         // (u_{-2}, u_{-1}) = true prev-filter output state
            #pragma unroll
            for (int i = 0; i < REGS/2; ++i) {
                const v2f S  = mk2(sig[2*i], sig[2*i+1]);
                const v2f Sh = F2(PA0p, mk2(S.x, S.x), S);
                const v2f U  = F2(PA2p, mk2(Up.x, Up.x), F2(PA1p, mk2(Up.y, Up.y), Sh));
                const v2f M1 = mk2(Up.y, U.x);
                const v2f C  = F2(B2v, Up, F2(B1v, M1, B0v*U));
                const v2f Ch = F2(A0v, mk2(C.x, C.x), C);
                const v2f Z  = F2(A2v, mk2(Zp.x, Zp.x), F2(A1v, mk2(Zp.y, Zp.y), Ch));
                sig[2*i] = C.x; sig[2*i+1] = C.y;
                Up = U; Zp = Z;
            }
            #pragma unroll
            for (int i = 0; i < LDSS/4; ++i) {
                const float4 v = sigh[i][tid];
                float4 r;
                #pragma unroll
                for (int h = 0; h < 2; ++h) {
                    const v2f S  = (h == 0) ? mk2(v.x, v.y) : mk2(v.z, v.w);
                    const v2f Sh = F2(PA0p, mk2(S.x, S.x), S);
                    const v2f U  = F2(PA2p, mk2(Up.x, Up.x), F2(PA1p, mk2(Up.y, Up.y), Sh));
                    const v2f M1 = mk2(Up.y, U.x);
                    const v2f C  = F2(B2v, Up, F2(B1v, M1, B0v*U));
                    const v2f Ch = F2(A0v, mk2(C.x, C.x), C);
                    const v2f Z  = F2(A2v, mk2(Zp.x, Zp.x), F2(A1v, mk2(Zp.y, Zp.y), Ch));
                    if (h == 0) { r.x = C.x; r.y = C.y; } else { r.z = C.x; r.w = C.y; }
                    Up = U; Zp = Z;
                }
                sigh[i][tid] = r;
            }
        }

        // ---- in-wave inclusive affine scan of (z_newest, z_second) ----
        float Sa = Zp.y, Sb = Zp.x;
        #pragma unroll
        for (int r = 0; r < 6; ++r) {
            const int d = 1 << r;
            const float4 M = *reinterpret_cast<const float4*>(mb + r*4);
            float ta = __shfl_up(Sa, d, 64);
            float tb = __shfl_up(Sb, d, 64);
            const bool act = (lane >= d);
            ta = act ? ta : 0.f;
            tb = act ? tb : 0.f;
            Sa = Sa + M.x * ta + M.y * tb;
            Sb = Sb + M.z * ta + M.w * tb;
        }
        const int buf = j & 1;
        if (lane == 63) waveP[buf][wid] = make_float2(Sa, Sb);
        __syncthreads();

        // ---- cross-wave: 4-level KS over 16 wave totals ----
        const float2 Pv = waveP[buf][lane & 15];
        float Tx = Pv.x, Ty = Pv.y;
        #pragma unroll
        for (int l = 0; l < 4; ++l) {
            const int d = 1 << l;
            const float4 M = *reinterpret_cast<const float4*>(mb + (6+l)*4);
            float tx = __shfl_up(Tx, d, 64);
            float ty = __shfl_up(Ty, d, 64);
            const bool act = (lane >= d);
            tx = act ? tx : 0.f;
            ty = act ? ty : 0.f;
            Tx = Tx + M.x * tx + M.y * ty;
            Ty = Ty + M.z * tx + M.w * ty;
        }
        float Vx = __shfl(Tx, wid - 1, 64);
        float Vy = __shfl(Ty, wid - 1, 64);
        if (wid == 0) { Vx = 0.f; Vy = 0.f; }
        #pragma unroll
        for (int r = 0; r < 6; ++r) {      // apply C^(64*lane)
            const float4 M = *reinterpret_cast<const float4*>(mb + r*4);
            const bool bit = (lane >> r) & 1;
            const float nx = M.x * Vx + M.y * Vy;
            const float ny = M.z * Vx + M.w * Vy;
            Vx = bit ? nx : Vx;
            Vy = bit ? ny : Vy;
        }
        {
            float Ea = __shfl_up(Sa, 1, 64);
            float Eb = __shfl_up(Sb, 1, 64);
            const bool l0 = (lane == 0);
            i1 = Vx + (l0 ? 0.f : Ea);
            i2 = Vy + (l0 ? 0.f : Eb);
        }
        PA0p = A0v; PA1p = A1v; PA2p = A2v;
    }

    // ---- tail: packed finalize of filter 9 + store ----
    {
        v2f Up = mk2(i2, i1);
        float4* dst = reinterpret_cast<float4*>(ob + (size_t)tid * CHUNK);
        #pragma unroll
        for (int i = 0; i < REGS/4; ++i) {
            float4 o;
            #pragma unroll
            for (int h = 0; h < 2; ++h) {
                const v2f S  = (h == 0) ? mk2(sig[4*i], sig[4*i+1]) : mk2(sig[4*i+2], sig[4*i+3]);
                const v2f Sh = F2(PA0p, mk2(S.x, S.x), S);
                const v2f U  = F2(PA2p, mk2(Up.x, Up.x), F2(PA1p, mk2(Up.y, Up.y), Sh));
                if (h == 0) { o.x = U.x; o.y = U.y; } else { o.z = U.x; o.w = U.y; }
                Up = U;
            }
            dst[i] = o;
        }
        #pragma unroll
        for (int i = 0; i < LDSS/4; ++i) {
            const float4 v = sigh[i][tid];
            float4 o;
            #pragma unroll
            for (int h = 0; h < 2; ++h) {
                const v2f S  = (h == 0) ? mk2(v.x, v.y) : mk2(v.z, v.w);
                const v2f Sh = F2(PA0p, mk2(S.x, S.x), S);
                const v2f U  = F2(PA2p, mk2(Up.x, Up.x), F2(PA1p, mk2(Up.y, Up.y), Sh));
                if (h == 0) { o.x = U.x; o.y = U.y; } else { o.z = U.x; o.w = U.y; }
                Up = U;
            }
            dst[REGS/4 + i] = o;
        }
    }
}

extern "C" void kernel_launch(void* const* d_in, const int* in_sizes, int n_in,
                              void* d_out, int out_size, void* d_ws, size_t ws_size,
                              hipStream_t stream) {
    const float* x    = (const float*)d_in[0];
    const float* w0   = (const float*)d_in[1];
    const float* qinv = (const float*)d_in[2];
    const float* gain = (const float*)d_in[3];
    float* out = (float*)d_out;
    float* ws  = (float*)d_ws;   // 256 * 576 * 4 B = 576 KiB

    const int B = in_sizes[1] / NFILT;   // 256 batches
    eq_precompute_kernel<<<B, 64, 0, stream>>>(w0, qinv, gain, ws);
    eq_cascade_kernel<<<B, THREADS, 0, stream>>>(x, out, ws);
}